// Round 14
// baseline (116.093 us; speedup 1.0000x reference)
//
#include <hip/hip_runtime.h>

#define N_POINTS  131072
#define N_ANCHORS 2048
#define THREADS   256
#define PTS_BLK   512                      // points per block = 32 tiles
#define NBX       (N_POINTS / PTS_BLK)     // 256 point-blocks
#define MCHUNKS   8                        // anchor chunks -> 2048 blocks
#define NTILES_M  (N_ANCHORS / 16)         // 128 anchor tiles
#define TILES_CH  (NTILES_M / MCHUNKS)     // 16 tiles per chunk (in regs)
#define LOG2E     1.4426950408889634f

typedef __attribute__((ext_vector_type(8))) short  short8;   // 8 bf16 = MFMA A/B frag
typedef __attribute__((ext_vector_type(4))) float  f32x4;    // MFMA C/D frag

// ---------------------------------------------------------------------------
// Split-GEMM formulation (R9-verified, absmax identical to scalar):
//   arg(n,m) = q_m + r_m.x_n + sp_m*|x_n|^2  via mfma_f32_16x16x32_bf16,
// 3 bf16 limbs per f32, 27/32 K-slots, residual ~2^-27.
// R14: the R9-R13 ledger shows wall pinned ~97k cy/SIMD with no saturated
// pipe -> per-iter global B-load latency is the binding chain. Fix: each
// wave register-caches its 16-tile B-chunk (64 VGPR) + cf (16 VGPR) ONCE;
// steady-state inner loop = MFMA + exp2 + fma on registers only.
// Partials via coalesced stores to ws (NOT atomics -- R12: 64B-line
// amplification) + tiny reduce kernel.
// ---------------------------------------------------------------------------

static __device__ __forceinline__ unsigned short f2bf(float v) {
    union { float f; unsigned u; } c; c.f = v;
    unsigned r = (c.u + 0x7FFFu + ((c.u >> 16) & 1u)) >> 16;   // RNE
    return (unsigned short)r;
}
static __device__ __forceinline__ float bf2f(unsigned short h) {
    union { unsigned u; float f; } c; c.u = ((unsigned)h) << 16;
    return c.f;
}
static __device__ __forceinline__ void split3(float v, unsigned short& h1,
                                              unsigned short& h2, unsigned short& h3) {
    h1 = f2bf(v); float v2 = v - bf2f(h1);
    h2 = f2bf(v2); float v3 = v2 - bf2f(h2);
    h3 = f2bf(v3);
}

#define BF_ONE ((short)0x3F80)

// ---------------------------------------------------------------------------
// prep_B: anchor-side fragments (layout unchanged since R9).
// ---------------------------------------------------------------------------
__global__ void prep_B(const float* __restrict__ aloc,
                       const float* __restrict__ coeffs,
                       const float* __restrict__ params,
                       short8* __restrict__ Bws,
                       float* __restrict__ cfws) {
    const int gid  = blockIdx.x * blockDim.x + threadIdx.x;   // [0, 8192)
    const int tile = gid >> 6;
    const int lane = gid & 63;
    const int kb   = lane >> 4;
    const int m    = tile * 16 + (lane & 15);

    const float a0 = aloc[3 * m + 0];
    const float a1 = aloc[3 * m + 1];
    const float a2 = aloc[3 * m + 2];
    const float w  = params[m];
    const float sp = -(0.5f * LOG2E) / (w * w);
    const float r0 = -2.0f * sp * a0;
    const float r1 = -2.0f * sp * a1;
    const float r2 = -2.0f * sp * a2;
    const float q  = sp * (a0 * a0 + a1 * a1 + a2 * a2);

    unsigned short r0a, r0b, r0c, r1a, r1b, r1c, r2a, r2b, r2c, spa, spb, spc, qa, qb, qc;
    split3(r0, r0a, r0b, r0c);
    split3(r1, r1a, r1b, r1c);
    split3(r2, r2a, r2b, r2c);
    split3(sp, spa, spb, spc);
    split3(q,  qa,  qb,  qc);

    short8 fr;
    switch (kb) {   // B-side limb pattern per group: {1,2,1,3,1,2}
    case 0: fr = (short8){(short)r0a,(short)r0b,(short)r0a,(short)r0c,(short)r0a,(short)r0b,(short)r1a,(short)r1b}; break;
    case 1: fr = (short8){(short)r1a,(short)r1c,(short)r1a,(short)r1b,(short)r2a,(short)r2b,(short)r2a,(short)r2c}; break;
    case 2: fr = (short8){(short)r2a,(short)r2b,(short)spa,(short)spb,(short)spa,(short)spc,(short)spa,(short)spb}; break;
    default:fr = (short8){(short)qa, (short)qb, (short)qc, 0, 0, 0, 0, 0}; break;
    }
    Bws[tile * 64 + lane] = fr;

    if (lane < 16) cfws[m] = coeffs[m];
}

// ---------------------------------------------------------------------------
// Main: grid (256, 8) x 256 thr = 2048 blocks, 4 waves each.
// Block stages 512 points (32 tiles) into LDS; wave w owns tiles w*8..w*8+7.
// Wave register-caches its chunk's 16 B-frags + 16 cf ONCE, then per
// point-tile: 1 ds_read (af) + 16x{MFMA + 4 exp2 + 4 fma} all-register,
// 16-lane shfl reduce, coalesced partial store.
// ---------------------------------------------------------------------------
__global__ __launch_bounds__(256, 4) void lp_main(
    const float* __restrict__ xloc,
    const short8* __restrict__ Bws,
    const float* __restrict__ cfws,
    float* __restrict__ part)
{
    __shared__ short8 sA[32][64];    // 32 point-tiles x 64 lanes, 32 KiB

    const int t = threadIdx.x;

    // ---- stage this block's 512 points as A-fragments (2048 entries) ----
    #pragma unroll
    for (int e0 = 0; e0 < 8; ++e0) {
        const int e    = t + e0 * 256;
        const int tl   = e >> 6;
        const int lane = e & 63;
        const int kb   = lane >> 4;
        const int p    = blockIdx.x * PTS_BLK + tl * 16 + (lane & 15);

        const float x = xloc[3 * p + 0];
        const float y = xloc[3 * p + 1];
        const float z = xloc[3 * p + 2];
        const float ss = fmaf(x, x, fmaf(y, y, z * z));

        unsigned short xa, xb, xc, ya, yb, yc, za, zb, zc, sa, sb, sc;
        split3(x,  xa, xb, xc);
        split3(y,  ya, yb, yc);
        split3(z,  za, zb, zc);
        split3(ss, sa, sb, sc);

        short8 fr;
        switch (kb) {   // A-side limb pattern per group: {1,1,2,1,3,2}
        case 0: fr = (short8){(short)xa,(short)xa,(short)xb,(short)xa,(short)xc,(short)xb,(short)ya,(short)ya}; break;
        case 1: fr = (short8){(short)yb,(short)ya,(short)yc,(short)yb,(short)za,(short)za,(short)zb,(short)za}; break;
        case 2: fr = (short8){(short)zc,(short)zb,(short)sa,(short)sa,(short)sb,(short)sa,(short)sc,(short)sb}; break;
        default:fr = (short8){BF_ONE, BF_ONE, BF_ONE, 0, 0, 0, 0, 0}; break;
        }
        sA[tl][lane] = fr;
    }

    const int wave = t >> 6;          // 0..3
    const int lane = t & 63;
    const int col  = lane & 15;
    const int kb   = lane >> 4;

    // ---- register-cache this block's anchor chunk (16 tiles) ----
    const int tm0 = blockIdx.y * TILES_CH;
    short8 breg[TILES_CH];
    float  cfr[TILES_CH];
    #pragma unroll
    for (int k = 0; k < TILES_CH; ++k) {
        breg[k] = Bws[(tm0 + k) * 64 + lane];
        cfr[k]  = cfws[(tm0 + k) * 16 + col];
    }

    __syncthreads();

    const f32x4 cz = {0.f, 0.f, 0.f, 0.f};
    float* __restrict__ pchunk = part + (size_t)blockIdx.y * N_POINTS;

    #pragma unroll 1
    for (int pt = 0; pt < 8; ++pt) {
        const int tl = wave * 8 + pt;
        const short8 af = sA[tl][lane];

        f32x4 acc = {0.f, 0.f, 0.f, 0.f};

        #pragma unroll
        for (int k = 0; k < TILES_CH; ++k) {
            f32x4 c = __builtin_amdgcn_mfma_f32_16x16x32_bf16(af, breg[k], cz, 0, 0, 0);
            #pragma unroll
            for (int r = 0; r < 4; ++r)
                acc[r] = fmaf(cfr[k], __builtin_amdgcn_exp2f(c[r]), acc[r]);
        }

        // reduce over the 16 anchor-col lanes of each group
        #pragma unroll
        for (int o = 1; o < 16; o <<= 1) {
            #pragma unroll
            for (int r = 0; r < 4; ++r)
                acc[r] += __shfl_xor(acc[r], o, 16);
        }

        if (col == 0) {
            const int pb = blockIdx.x * PTS_BLK + tl * 16 + kb * 4;
            #pragma unroll
            for (int r = 0; r < 4; ++r)
                pchunk[pb + r] = acc[r];
        }
    }
}

// ---------------------------------------------------------------------------
// reduce: out[n] = sum over 8 chunks of part[c][n]. float4-vectorized.
// ---------------------------------------------------------------------------
__global__ void reduce_parts(const float4* __restrict__ part4,
                             float4* __restrict__ out4) {
    const int i = blockIdx.x * blockDim.x + threadIdx.x;   // [0, 32768)
    float4 s = part4[i];
    #pragma unroll
    for (int c = 1; c < MCHUNKS; ++c) {
        const float4 p = part4[c * (N_POINTS / 4) + i];
        s.x += p.x; s.y += p.y; s.z += p.z; s.w += p.w;
    }
    out4[i] = s;
}

extern "C" void kernel_launch(void* const* d_in, const int* in_sizes, int n_in,
                              void* d_out, int out_size, void* d_ws, size_t ws_size,
                              hipStream_t stream) {
    const float* xloc   = (const float*)d_in[0];   // [131072,3]
    const float* aloc   = (const float*)d_in[1];   // [2048,3]
    const float* coeffs = (const float*)d_in[2];   // [2048]
    const float* params = (const float*)d_in[3];   // [2048]
    float* out = (float*)d_out;                    // [131072] f32

    short8* Bws  = (short8*)d_ws;                                  // 128 KiB
    float*  cfws = (float*)((char*)d_ws + 128 * 1024);             // 8 KiB
    float*  part = (float*)((char*)d_ws + 256 * 1024);             // 8 x 512 KiB

    prep_B<<<dim3((NTILES_M * 64) / 256), dim3(256), 0, stream>>>(
        aloc, coeffs, params, Bws, cfws);

    lp_main<<<dim3(NBX, MCHUNKS), dim3(THREADS), 0, stream>>>(
        xloc, Bws, cfws, part);

    reduce_parts<<<dim3(N_POINTS / 4 / 256), dim3(256), 0, stream>>>(
        (const float4*)part, (float4*)out);
}